// Round 9
// baseline (142.160 us; speedup 1.0000x reference)
//
#include <hip/hip_runtime.h>
#include <math.h>

#define B_N 2048
#define D_FT 784
#define K_N 50
#define L_N 6
#define LOG2PI_F 1.8378770664093453f

// ---- output layout (floats), concatenated in reference return order ----
#define OUT_PW 0
#define OUT_M  (B_N)                              // 2048
#define OUT_A  (OUT_M + B_N*D_FT)                 // 1607680
#define OUT_D  (OUT_A + B_N*D_FT*6)               // 11241472

// ---- workspace layout (float offsets) ----
#define WS_SCORES 0                                // [K][B]  (also holds SJL pre-accum)
#define WS_PQ     (WS_SCORES + K_N*B_N)            // [K][27][B] 2764800
#define WS_XT     (WS_PQ + K_N*27*B_N)             // [D/4][B] float4 = D*B floats
#define WS_JBT    (WS_XT + D_FT*B_N)               // [25][B]    51200

#define IDX(i,j) ((i)*((i)+1)/2 + (j))   // packed lower, i>=j

typedef float v2f __attribute__((ext_vector_type(2)));

// VOP3P packed f32 (same FLOP rate as scalar fma, half the issue slots).
#define PK_FMA(acc, a, b) asm("v_pk_fma_f32 %0, %1, %2, %0" : "+v"(acc) : "v"(a), "v"(b))

// ---------- 6x6 packed-lower Cholesky ----------
__device__ __forceinline__ void chol6(const float* P, float* L, float* rd, float* sumlog) {
    float sl = 0.f;
    #pragma unroll
    for (int j = 0; j < 6; ++j) {
        float s = P[IDX(j,j)];
        #pragma unroll
        for (int m = 0; m < j; ++m) s -= L[IDX(j,m)] * L[IDX(j,m)];
        float d = sqrtf(s);
        L[IDX(j,j)] = d;
        float r = 1.0f / d;
        rd[j] = r;
        sl += logf(d);
        #pragma unroll
        for (int i = j + 1; i < 6; ++i) {
            float t = P[IDX(i,j)];
            #pragma unroll
            for (int m = 0; m < j; ++m) t -= L[IDX(i,m)] * L[IDX(j,m)];
            L[IDX(i,j)] = t * r;
        }
    }
    *sumlog = sl;
}

// ---------- K0: fused transpose (X -> Xt4) + packbits (J -> JbT) ----------
__global__ __launch_bounds__(1024) void k_prep(const float* __restrict__ X,
                                               const int* __restrict__ J,
                                               float4* __restrict__ Xt4,
                                               unsigned* __restrict__ JbT) {
    const int bid = blockIdx.x;
    const int tid = threadIdx.x;
    if (bid < 448) {
        __shared__ float4 tile[32][33];
        int tx = tid & 31, ty = tid >> 5;
        int d4b = (bid % 7) * 32;
        int bb  = (bid / 7) * 32;
        int d4 = d4b + tx;
        if (d4 < D_FT / 4)
            tile[ty][tx] = *(const float4*)&X[(size_t)(bb + ty) * D_FT + d4 * 4];
        __syncthreads();
        int d4o = d4b + ty;
        if (d4o < D_FT / 4)
            Xt4[(size_t)d4o * B_N + (bb + tx)] = tile[tx][ty];
    } else {
        int t = (bid - 448) * 1024 + tid;    // 65536 threads = 2048 b x 32 w
        int b = t >> 5;
        int w = t & 31;
        if (w >= 25) return;
        int d0 = w * 32;
        int n = D_FT - d0; if (n > 32) n = 32;
        unsigned u = 0;
        for (int j = 0; j < n; ++j)
            u |= (J[(size_t)b * D_FT + d0 + j] != 0 ? 1u : 0u) << j;
        JbT[(size_t)w * B_N + b] = u;
    }
}

// ---------- K0c: SJL[k][b] = sum_d Jf[b,d]*logD[k,d]  (into scores buffer) ----------
__global__ __launch_bounds__(256) void k_jld(const float* __restrict__ logD,
                                             const unsigned* __restrict__ JbT,
                                             float* __restrict__ SJL) {
    __shared__ float ld[800];
    const int k  = blockIdx.x >> 3;
    const int bt = blockIdx.x & 7;
    for (int i = threadIdx.x; i < 800; i += 256)
        ld[i] = (i < D_FT) ? logD[(size_t)k * D_FT + i] : 0.f;
    __syncthreads();
    const int b = bt * 256 + threadIdx.x;
    float jl = 0.f;
    for (int w = 0; w < 25; ++w) {
        unsigned mw = JbT[(size_t)w * B_N + b];
        const float* lw = &ld[w * 32];
        #pragma unroll
        for (int dd = 0; dd < 32; ++dd)
            jl += ((mw >> dd) & 1u) ? lw[dd] : 0.f;
    }
    SJL[(size_t)k * B_N + b] = jl;
}

// ---------- K1: per-(sample,k) accumulation + loglik ----------
// 256 threads = 64 samples x 4 d-quarters; d staged in two chunks through one
// 12.8 KB LDS record buffer. Per mask-word: 8 x-float4 loads HOISTED into a
// register array (all VMEM in flight before the 16 ACC_PAIRs) to hide L2
// latency; full unroll keeps indices static (no scratch).
// Pair record (16 floats): f4[0..2] = a~0..a~5 pair-interleaved,
// f4[3]={sa0,sa1,-mu0,-mu1}, a~ = sa*a, sa = exp(-logD/2).
// Math (m^2=m): u_i = m*a~_i; P_ij += u_i*u_j; z = (m*sa)*(x-mu);
//               q_j += z*u_j; quad += z*z.
// NOTE: launch_bounds MUST stay (256,4): min-waves>=6 makes the allocator
// pick a spill schedule (r3: 32 VGPR/1.5GB; r4: 40 VGPR/635MB).
// NOTE2: records MUST be LDS-resident (r7: global records lost 24 us to VMEM).
#define ACC_PAIR(pi, dd, x0, x1) do { \
    const float4 f0 = sm4[(size_t)(pi) * 4 + 0]; \
    const float4 f1 = sm4[(size_t)(pi) * 4 + 1]; \
    const float4 f2 = sm4[(size_t)(pi) * 4 + 2]; \
    const float4 f3 = sm4[(size_t)(pi) * 4 + 3]; \
    v2f m2;  m2.x = (float)((mw >> (dd)) & 1u); m2.y = (float)((mw >> ((dd)+1)) & 1u); \
    v2f x2;  x2.x = (x0); x2.y = (x1); \
    v2f sa2;  sa2.x = f3.x;  sa2.y = f3.y; \
    v2f nmu2; nmu2.x = f3.z; nmu2.y = f3.w; \
    v2f xm2 = x2 + nmu2; \
    v2f w2  = m2 * sa2; \
    v2f z2  = w2 * xm2; \
    v2f a0; a0.x = f0.x; a0.y = f0.y;  v2f a1; a1.x = f0.z; a1.y = f0.w; \
    v2f a2; a2.x = f1.x; a2.y = f1.y;  v2f a3; a3.x = f1.z; a3.y = f1.w; \
    v2f a4; a4.x = f2.x; a4.y = f2.y;  v2f a5; a5.x = f2.z; a5.y = f2.w; \
    v2f u0 = m2 * a0, u1 = m2 * a1, u2 = m2 * a2; \
    v2f u3 = m2 * a3, u4 = m2 * a4, u5 = m2 * a5; \
    PK_FMA(Pm2[0],  u0, u0); \
    PK_FMA(Pm2[1],  u1, u0); PK_FMA(Pm2[2],  u1, u1); \
    PK_FMA(Pm2[3],  u2, u0); PK_FMA(Pm2[4],  u2, u1); PK_FMA(Pm2[5],  u2, u2); \
    PK_FMA(Pm2[6],  u3, u0); PK_FMA(Pm2[7],  u3, u1); PK_FMA(Pm2[8],  u3, u2); PK_FMA(Pm2[9],  u3, u3); \
    PK_FMA(Pm2[10], u4, u0); PK_FMA(Pm2[11], u4, u1); PK_FMA(Pm2[12], u4, u2); PK_FMA(Pm2[13], u4, u3); PK_FMA(Pm2[14], u4, u4); \
    PK_FMA(Pm2[15], u5, u0); PK_FMA(Pm2[16], u5, u1); PK_FMA(Pm2[17], u5, u2); PK_FMA(Pm2[18], u5, u3); PK_FMA(Pm2[19], u5, u4); PK_FMA(Pm2[20], u5, u5); \
    PK_FMA(qv2[0], z2, u0); PK_FMA(qv2[1], z2, u1); PK_FMA(qv2[2], z2, u2); \
    PK_FMA(qv2[3], z2, u3); PK_FMA(qv2[4], z2, u4); PK_FMA(qv2[5], z2, u5); \
    PK_FMA(quad2, z2, z2); \
} while (0)

__global__ __launch_bounds__(256, 4) void k_accum(
        const float4* __restrict__ Xt4, const unsigned* __restrict__ JbT,
        const float* __restrict__ A, const float* __restrict__ MU,
        const float* __restrict__ logD, const float* __restrict__ PI,
        float* __restrict__ scores, float* __restrict__ Pq) {
    __shared__ float4 sm4[200 * 4];     // 12800 B records; aliased as merge slab
    float* smem = (float*)sm4;
    const int k   = blockIdx.x >> 5;
    const int tid = threadIdx.x;
    const int s   = tid & 63;
    const int h   = tid >> 6;           // d-quarter 0..3
    const int b   = (blockIdx.x & 31) * 64 + s;

    v2f Pm2[21], qv2[6], quad2;
    #pragma unroll
    for (int t = 0; t < 21; ++t) { Pm2[t].x = 0.f; Pm2[t].y = 0.f; }
    #pragma unroll
    for (int t = 0; t < 6; ++t) { qv2[t].x = 0.f; qv2[t].y = 0.f; }
    quad2.x = 0.f; quad2.y = 0.f;
    int nob = 0;

    for (int c = 0; c < 2; ++c) {
        const int dbase = c ? 384 : 0;
        const int npair = c ? 200 : 192;
        __syncthreads();                 // all quarters done reading old records
        for (int p = tid; p < npair; p += 256) {
            const int d0 = dbase + 2 * p;
            const float* ar0 = A + ((size_t)k * D_FT + d0) * 6;
            const float* ar1 = ar0 + 6;
            float sa0 = expf(-0.5f * logD[(size_t)k * D_FT + d0]);
            float sa1 = expf(-0.5f * logD[(size_t)k * D_FT + d0 + 1]);
            float4 f0, f1, f2, f3;
            f0.x = sa0 * ar0[0]; f0.y = sa1 * ar1[0]; f0.z = sa0 * ar0[1]; f0.w = sa1 * ar1[1];
            f1.x = sa0 * ar0[2]; f1.y = sa1 * ar1[2]; f1.z = sa0 * ar0[3]; f1.w = sa1 * ar1[3];
            f2.x = sa0 * ar0[4]; f2.y = sa1 * ar1[4]; f2.z = sa0 * ar0[5]; f2.w = sa1 * ar1[5];
            f3.x = sa0; f3.y = sa1;
            f3.z = -MU[(size_t)k * D_FT + d0];
            f3.w = -MU[(size_t)k * D_FT + d0 + 1];
            sm4[(size_t)p * 4 + 0] = f0;
            sm4[(size_t)p * 4 + 1] = f1;
            sm4[(size_t)p * 4 + 2] = f2;
            sm4[(size_t)p * 4 + 3] = f3;
        }
        __syncthreads();

        const int wb = (c ? 12 : 0) + 3 * h;
        for (int w = wb; w < wb + 3; ++w) {
            const unsigned mw = JbT[(size_t)w * B_N + b];
            nob += __popc(mw);
            const int plb = w * 16 - (dbase >> 1);   // local pair base
            const float4* xp = Xt4 + (size_t)(w * 8) * B_N + b;
            float4 xv[8];
            #pragma unroll
            for (int g = 0; g < 8; ++g) xv[g] = xp[(size_t)g * B_N];
            #pragma unroll
            for (int g = 0; g < 8; ++g) {
                ACC_PAIR(plb + 2 * g,     g * 4,     xv[g].x, xv[g].y);
                ACC_PAIR(plb + 2 * g + 1, g * 4 + 2, xv[g].z, xv[g].w);
            }
        }
        if (c == 1 && h == 3) {  // tail word 24: bits 0..15 valid
            const unsigned mw = JbT[(size_t)24 * B_N + b];
            nob += __popc(mw);
            const int plb = 24 * 16 - 192;           // = 192
            const float4* xp = Xt4 + (size_t)(24 * 8) * B_N + b;
            float4 xv[4];
            #pragma unroll
            for (int g = 0; g < 4; ++g) xv[g] = xp[(size_t)g * B_N];
            #pragma unroll
            for (int g = 0; g < 4; ++g) {
                ACC_PAIR(plb + 2 * g,     g * 4,     xv[g].x, xv[g].y);
                ACC_PAIR(plb + 2 * g + 1, g * 4 + 2, xv[g].z, xv[g].w);
            }
        }
    }

    // horizontal add of packed halves
    float Pm[21], qv[6], quad;
    #pragma unroll
    for (int t = 0; t < 21; ++t) Pm[t] = Pm2[t].x + Pm2[t].y;
    #pragma unroll
    for (int t = 0; t < 6; ++t) qv[t] = qv2[t].x + qv2[t].y;
    quad = quad2.x + quad2.y;

    __syncthreads();                     // records dead; slab aliases them
    float* red = smem;                   // 64 x 33 slab, conflict-free
    #define SLAB_WR do { float* o = &red[s * 33]; \
        _Pragma("unroll") for (int t = 0; t < 21; ++t) o[t] = Pm[t]; \
        _Pragma("unroll") for (int t = 0; t < 6; ++t) o[21 + t] = qv[t]; \
        o[27] = quad; o[28] = (float)nob; } while (0)
    #define SLAB_ADD do { const float* o = &red[s * 33]; \
        _Pragma("unroll") for (int t = 0; t < 21; ++t) Pm[t] += o[t]; \
        _Pragma("unroll") for (int t = 0; t < 6; ++t) qv[t] += o[21 + t]; \
        quad += o[27]; nob += (int)o[28]; } while (0)

    if (h == 1) SLAB_WR;
    __syncthreads();
    if (h == 0) SLAB_ADD;
    __syncthreads();
    if (h == 3) SLAB_WR;
    __syncthreads();
    if (h == 2) SLAB_ADD;
    __syncthreads();
    if (h == 2) SLAB_WR;
    __syncthreads();
    if (h == 0) {
        SLAB_ADD;
        float nobs = (float)nob;

        // jld precomputed by k_jld into the scores buffer (read before overwrite)
        float jld = scores[(size_t)k * B_N + b];

        // P = I + sum
        Pm[0] += 1.f; Pm[2] += 1.f; Pm[5] += 1.f; Pm[9] += 1.f; Pm[14] += 1.f; Pm[20] += 1.f;

        float Lm[21], rd[6], sumlog;
        chol6(Pm, Lm, rd, &sumlog);
        float y[6];
        #pragma unroll
        for (int j = 0; j < 6; ++j) {
            float sv = qv[j];
            #pragma unroll
            for (int m = 0; m < j; ++m) sv -= Lm[IDX(j,m)] * y[m];
            y[j] = sv * rd[j];
        }
        float yy = 0.f;
        #pragma unroll
        for (int j = 0; j < 6; ++j) yy += y[j] * y[j];
        float logdet = 2.f * sumlog + jld;
        float ll = -0.5f * ((quad - yy) + logdet + nobs * LOG2PI_F);
        float score = ll + PI[k];

        scores[(size_t)k * B_N + b] = score;
        float* pq = Pq + (size_t)k * 27 * B_N + b;
        #pragma unroll
        for (int t = 0; t < 21; ++t) pq[(size_t)t * B_N] = Pm[t];
        #pragma unroll
        for (int t = 0; t < 6; ++t) pq[(size_t)(21 + t) * B_N] = qv[t];
    }
}

// ---------- KD: fused argmax + latent solve + output write (one block per b) ----------
__global__ __launch_bounds__(256) void k_outsel(
        const float* __restrict__ scores, const float* __restrict__ Pq,
        const float* __restrict__ A, const float* __restrict__ MU,
        const float* __restrict__ logD, float* __restrict__ out) {
    const int b = blockIdx.x;
    const int tid = threadIdx.x;

    // argmax over K (redundant in all threads; loads broadcast from L2)
    float best = scores[b];
    int bc = 0;
    for (int kk = 1; kk < K_N; ++kk) {
        float sv = scores[(size_t)kk * B_N + b];
        if (sv > best) { best = sv; bc = kk; }
    }
    if (tid == 0) out[OUT_PW + b] = 1.0f;

    // redundant per-thread 6x6 solve (cheap; avoids k_select kernel + round-trip)
    float Pm[21], qv[6];
    const float* pq = Pq + (size_t)bc * 27 * B_N + b;
    #pragma unroll
    for (int t = 0; t < 21; ++t) Pm[t] = pq[(size_t)t * B_N];
    #pragma unroll
    for (int t = 0; t < 6; ++t) qv[t] = pq[(size_t)(21 + t) * B_N];

    float Lm[21], rd[6], dummy;
    chol6(Pm, Lm, rd, &dummy);

    float y[6];
    #pragma unroll
    for (int j = 0; j < 6; ++j) {
        float sv = qv[j];
        #pragma unroll
        for (int m = 0; m < j; ++m) sv -= Lm[IDX(j,m)] * y[m];
        y[j] = sv * rd[j];
    }
    float mz[6];
    #pragma unroll
    for (int ii = 5; ii >= 0; --ii) {
        float sv = y[ii];
        #pragma unroll
        for (int j = ii + 1; j < 6; ++j) sv -= Lm[IDX(j,ii)] * mz[j];
        mz[ii] = sv * rd[ii];
    }
    float Li[21];
    #pragma unroll
    for (int j = 0; j < 6; ++j) {
        Li[IDX(j,j)] = rd[j];
        #pragma unroll
        for (int i = j + 1; i < 6; ++i) {
            float sv = 0.f;
            #pragma unroll
            for (int m = j; m < i; ++m) sv += Lm[IDX(i,m)] * Li[IDX(m,j)];
            Li[IDX(i,j)] = -sv * rd[i];
        }
    }
    float cov[21];
    #pragma unroll
    for (int i = 0; i < 6; ++i) {
        #pragma unroll
        for (int j = 0; j <= i; ++j) {
            float sv = 0.f;
            #pragma unroll
            for (int m = i; m < 6; ++m) sv += Li[IDX(m,i)] * Li[IDX(m,j)];
            cov[IDX(i,j)] = sv;
        }
    }
    float Lz[21], rd2[6];
    chol6(cov, Lz, rd2, &dummy);

    const int c = bc;
    for (int d = tid; d < D_FT; d += 256) {
        const float* ar = A + ((size_t)c * D_FT + d) * 6;
        float a[6];
        #pragma unroll
        for (int i = 0; i < 6; ++i) a[i] = ar[i];
        float mu = MU[(size_t)c * D_FT + d];
        float ld = logD[(size_t)c * D_FT + d];
        float m = mu;
        #pragma unroll
        for (int i = 0; i < 6; ++i) m += a[i] * mz[i];
        out[OUT_M + (size_t)b * D_FT + d] = m;
        out[OUT_D + (size_t)b * D_FT + d] = expf(ld);
        float* ao = out + OUT_A + ((size_t)b * D_FT + d) * 6;
        #pragma unroll
        for (int j = 0; j < 6; ++j) {
            float sv = 0.f;
            #pragma unroll
            for (int i = j; i < 6; ++i) sv += a[i] * Lz[IDX(i,j)];
            ao[j] = sv;
        }
    }
}

extern "C" void kernel_launch(void* const* d_in, const int* in_sizes, int n_in,
                              void* d_out, int out_size, void* d_ws, size_t ws_size,
                              hipStream_t stream) {
    (void)in_sizes; (void)n_in; (void)out_size; (void)ws_size;
    const float* X    = (const float*)d_in[0];
    const int*   J    = (const int*)d_in[1];
    const float* MU   = (const float*)d_in[2];
    const float* A    = (const float*)d_in[3];
    const float* logD = (const float*)d_in[4];
    const float* PI   = (const float*)d_in[5];
    float* out = (float*)d_out;
    float* ws  = (float*)d_ws;

    float*    scores = ws + WS_SCORES;   // pre-accum: SJL (jld terms)
    float*    Pq     = ws + WS_PQ;
    float4*   Xt4    = (float4*)(ws + WS_XT);
    unsigned* JbT    = (unsigned*)(ws + WS_JBT);

    k_prep<<<512, 1024, 0, stream>>>(X, J, Xt4, JbT);

    k_jld<<<K_N * 8, 256, 0, stream>>>(logD, JbT, scores);

    k_accum<<<32 * K_N, 256, 0, stream>>>(Xt4, JbT, A, MU, logD, PI, scores, Pq);

    k_outsel<<<B_N, 256, 0, stream>>>(scores, Pq, A, MU, logD, out);
}

// Round 10
// 138.729 us; speedup vs baseline: 1.0247x; 1.0247x over previous
//
#include <hip/hip_runtime.h>
#include <math.h>

#define B_N 2048
#define D_FT 784
#define K_N 50
#define L_N 6
#define LOG2PI_F 1.8378770664093453f

// ---- output layout (floats), concatenated in reference return order ----
#define OUT_PW 0
#define OUT_M  (B_N)                              // 2048
#define OUT_A  (OUT_M + B_N*D_FT)                 // 1607680
#define OUT_D  (OUT_A + B_N*D_FT*6)               // 11241472

// ---- workspace layout (float offsets) ----
#define WS_SCORES 0                                // [K][B]  (also holds SJL pre-accum)
#define WS_PQ     (WS_SCORES + K_N*B_N)            // [K][27][B] 2764800
#define WS_XT     (WS_PQ + K_N*27*B_N)             // [D/4][B] float4 = D*B floats
#define WS_JBT    (WS_XT + D_FT*B_N)               // [25][B]    51200

#define IDX(i,j) ((i)*((i)+1)/2 + (j))   // packed lower, i>=j

typedef float v2f __attribute__((ext_vector_type(2)));

// VOP3P packed f32 (halves VALU issue slots for the accumulator updates).
#define PK_FMA(acc, a, b) asm("v_pk_fma_f32 %0, %1, %2, %0" : "+v"(acc) : "v"(a), "v"(b))

// ---------- 6x6 packed-lower Cholesky ----------
__device__ __forceinline__ void chol6(const float* P, float* L, float* rd, float* sumlog) {
    float sl = 0.f;
    #pragma unroll
    for (int j = 0; j < 6; ++j) {
        float s = P[IDX(j,j)];
        #pragma unroll
        for (int m = 0; m < j; ++m) s -= L[IDX(j,m)] * L[IDX(j,m)];
        float d = sqrtf(s);
        L[IDX(j,j)] = d;
        float r = 1.0f / d;
        rd[j] = r;
        sl += logf(d);
        #pragma unroll
        for (int i = j + 1; i < 6; ++i) {
            float t = P[IDX(i,j)];
            #pragma unroll
            for (int m = 0; m < j; ++m) t -= L[IDX(i,m)] * L[IDX(j,m)];
            L[IDX(i,j)] = t * r;
        }
    }
    *sumlog = sl;
}

// ---------- K0: fused transpose (X -> Xt4) + packbits (J -> JbT) ----------
__global__ __launch_bounds__(1024) void k_prep(const float* __restrict__ X,
                                               const int* __restrict__ J,
                                               float4* __restrict__ Xt4,
                                               unsigned* __restrict__ JbT) {
    const int bid = blockIdx.x;
    const int tid = threadIdx.x;
    if (bid < 448) {
        __shared__ float4 tile[32][33];
        int tx = tid & 31, ty = tid >> 5;
        int d4b = (bid % 7) * 32;
        int bb  = (bid / 7) * 32;
        int d4 = d4b + tx;
        if (d4 < D_FT / 4)
            tile[ty][tx] = *(const float4*)&X[(size_t)(bb + ty) * D_FT + d4 * 4];
        __syncthreads();
        int d4o = d4b + ty;
        if (d4o < D_FT / 4)
            Xt4[(size_t)d4o * B_N + (bb + tx)] = tile[tx][ty];
    } else {
        int t = (bid - 448) * 1024 + tid;    // 65536 threads = 2048 b x 32 w
        int b = t >> 5;
        int w = t & 31;
        if (w >= 25) return;
        int d0 = w * 32;
        int n = D_FT - d0; if (n > 32) n = 32;
        unsigned u = 0;
        for (int j = 0; j < n; ++j)
            u |= (J[(size_t)b * D_FT + d0 + j] != 0 ? 1u : 0u) << j;
        JbT[(size_t)w * B_N + b] = u;
    }
}

// ---------- K0c: SJL[k][b] = sum_d Jf[b,d]*logD[k,d]  (into scores buffer) ----------
__global__ __launch_bounds__(256) void k_jld(const float* __restrict__ logD,
                                             const unsigned* __restrict__ JbT,
                                             float* __restrict__ SJL) {
    __shared__ float ld[800];
    const int k  = blockIdx.x >> 3;
    const int bt = blockIdx.x & 7;
    for (int i = threadIdx.x; i < 800; i += 256)
        ld[i] = (i < D_FT) ? logD[(size_t)k * D_FT + i] : 0.f;
    __syncthreads();
    const int b = bt * 256 + threadIdx.x;
    float jl0 = 0.f, jl1 = 0.f;
    for (int w = 0; w < 25; ++w) {
        unsigned mw = JbT[(size_t)w * B_N + b];
        const float* lw = &ld[w * 32];
        #pragma unroll
        for (int dd = 0; dd < 32; dd += 2) {
            jl0 += ((mw >> dd) & 1u) ? lw[dd] : 0.f;
            jl1 += ((mw >> (dd + 1)) & 1u) ? lw[dd + 1] : 0.f;
        }
    }
    SJL[(size_t)k * B_N + b] = jl0 + jl1;
}

// ---------- K1: per-(sample,k) accumulation + loglik ----------
// 256 threads = 64 samples x 4 d-quarters; d staged in two chunks through one
// 12.8 KB LDS record buffer (r8 streaming body — PROVEN 84 us / 64 VGPR).
// Pair record (16 floats): f4[0..2] = a~0..a~5 pair-interleaved,
// f4[3]={sa0,sa1,-mu0,-mu1}, a~ = sa*a, sa = exp(-logD/2).
// Math (m^2=m): u_i = m*a~_i; P_ij += u_i*u_j; z = (m*sa)*(x-mu);
//               q_j += z*u_j; quad += z*z.
// NOTE (allocator): this body compiles to exactly 64 VGPR and the allocator
// PINS there — any register-hoisting (r9 xv[8]) spills to scratch instead of
// growing into the 65-128 band. Do not hoist. launch_bounds must stay (256,4):
// min-waves>=6 forces a catastrophic spill schedule (r3/r4).
// NOTE2: records must be LDS-resident (r7: global records lost 24 us to VMEM).
#define ACC_PAIR(pi, dd, x0, x1) do { \
    const float4 f0 = sm4[(size_t)(pi) * 4 + 0]; \
    const float4 f1 = sm4[(size_t)(pi) * 4 + 1]; \
    const float4 f2 = sm4[(size_t)(pi) * 4 + 2]; \
    const float4 f3 = sm4[(size_t)(pi) * 4 + 3]; \
    v2f m2;  m2.x = (float)((mw >> (dd)) & 1u); m2.y = (float)((mw >> ((dd)+1)) & 1u); \
    v2f x2;  x2.x = (x0); x2.y = (x1); \
    v2f sa2;  sa2.x = f3.x;  sa2.y = f3.y; \
    v2f nmu2; nmu2.x = f3.z; nmu2.y = f3.w; \
    v2f xm2 = x2 + nmu2; \
    v2f w2  = m2 * sa2; \
    v2f z2  = w2 * xm2; \
    v2f a0; a0.x = f0.x; a0.y = f0.y;  v2f a1; a1.x = f0.z; a1.y = f0.w; \
    v2f a2; a2.x = f1.x; a2.y = f1.y;  v2f a3; a3.x = f1.z; a3.y = f1.w; \
    v2f a4; a4.x = f2.x; a4.y = f2.y;  v2f a5; a5.x = f2.z; a5.y = f2.w; \
    v2f u0 = m2 * a0, u1 = m2 * a1, u2 = m2 * a2; \
    v2f u3 = m2 * a3, u4 = m2 * a4, u5 = m2 * a5; \
    PK_FMA(Pm2[0],  u0, u0); \
    PK_FMA(Pm2[1],  u1, u0); PK_FMA(Pm2[2],  u1, u1); \
    PK_FMA(Pm2[3],  u2, u0); PK_FMA(Pm2[4],  u2, u1); PK_FMA(Pm2[5],  u2, u2); \
    PK_FMA(Pm2[6],  u3, u0); PK_FMA(Pm2[7],  u3, u1); PK_FMA(Pm2[8],  u3, u2); PK_FMA(Pm2[9],  u3, u3); \
    PK_FMA(Pm2[10], u4, u0); PK_FMA(Pm2[11], u4, u1); PK_FMA(Pm2[12], u4, u2); PK_FMA(Pm2[13], u4, u3); PK_FMA(Pm2[14], u4, u4); \
    PK_FMA(Pm2[15], u5, u0); PK_FMA(Pm2[16], u5, u1); PK_FMA(Pm2[17], u5, u2); PK_FMA(Pm2[18], u5, u3); PK_FMA(Pm2[19], u5, u4); PK_FMA(Pm2[20], u5, u5); \
    PK_FMA(qv2[0], z2, u0); PK_FMA(qv2[1], z2, u1); PK_FMA(qv2[2], z2, u2); \
    PK_FMA(qv2[3], z2, u3); PK_FMA(qv2[4], z2, u4); PK_FMA(qv2[5], z2, u5); \
    PK_FMA(quad2, z2, z2); \
} while (0)

__global__ __launch_bounds__(256, 4) void k_accum(
        const float4* __restrict__ Xt4, const unsigned* __restrict__ JbT,
        const float* __restrict__ A, const float* __restrict__ MU,
        const float* __restrict__ logD, const float* __restrict__ PI,
        float* __restrict__ scores, float* __restrict__ Pq) {
    __shared__ float4 sm4[200 * 4];     // 12800 B records; aliased as merge slab
    float* smem = (float*)sm4;
    const int k   = blockIdx.x >> 5;
    const int tid = threadIdx.x;
    const int s   = tid & 63;
    const int h   = tid >> 6;           // d-quarter 0..3
    const int b   = (blockIdx.x & 31) * 64 + s;

    v2f Pm2[21], qv2[6], quad2;
    #pragma unroll
    for (int t = 0; t < 21; ++t) { Pm2[t].x = 0.f; Pm2[t].y = 0.f; }
    #pragma unroll
    for (int t = 0; t < 6; ++t) { qv2[t].x = 0.f; qv2[t].y = 0.f; }
    quad2.x = 0.f; quad2.y = 0.f;
    int nob = 0;

    for (int c = 0; c < 2; ++c) {
        const int dbase = c ? 384 : 0;
        const int npair = c ? 200 : 192;
        __syncthreads();                 // all quarters done reading old records
        for (int p = tid; p < npair; p += 256) {
            const int d0 = dbase + 2 * p;
            const float* ar0 = A + ((size_t)k * D_FT + d0) * 6;
            const float* ar1 = ar0 + 6;
            float sa0 = expf(-0.5f * logD[(size_t)k * D_FT + d0]);
            float sa1 = expf(-0.5f * logD[(size_t)k * D_FT + d0 + 1]);
            float4 f0, f1, f2, f3;
            f0.x = sa0 * ar0[0]; f0.y = sa1 * ar1[0]; f0.z = sa0 * ar0[1]; f0.w = sa1 * ar1[1];
            f1.x = sa0 * ar0[2]; f1.y = sa1 * ar1[2]; f1.z = sa0 * ar0[3]; f1.w = sa1 * ar1[3];
            f2.x = sa0 * ar0[4]; f2.y = sa1 * ar1[4]; f2.z = sa0 * ar0[5]; f2.w = sa1 * ar1[5];
            f3.x = sa0; f3.y = sa1;
            f3.z = -MU[(size_t)k * D_FT + d0];
            f3.w = -MU[(size_t)k * D_FT + d0 + 1];
            sm4[(size_t)p * 4 + 0] = f0;
            sm4[(size_t)p * 4 + 1] = f1;
            sm4[(size_t)p * 4 + 2] = f2;
            sm4[(size_t)p * 4 + 3] = f3;
        }
        __syncthreads();

        const int wb = (c ? 12 : 0) + 3 * h;
        for (int w = wb; w < wb + 3; ++w) {
            const unsigned mw = JbT[(size_t)w * B_N + b];
            nob += __popc(mw);
            const int plb = w * 16 - (dbase >> 1);   // local pair base
            const float4* xp = Xt4 + (size_t)(w * 8) * B_N + b;
            #pragma unroll 2
            for (int g = 0; g < 8; ++g) {
                float4 xv = xp[(size_t)g * B_N];
                ACC_PAIR(plb + 2 * g,     g * 4,     xv.x, xv.y);
                ACC_PAIR(plb + 2 * g + 1, g * 4 + 2, xv.z, xv.w);
            }
        }
        if (c == 1 && h == 3) {  // tail word 24: bits 0..15 valid
            const unsigned mw = JbT[(size_t)24 * B_N + b];
            nob += __popc(mw);
            const int plb = 24 * 16 - 192;           // = 192
            const float4* xp = Xt4 + (size_t)(24 * 8) * B_N + b;
            #pragma unroll
            for (int g = 0; g < 4; ++g) {
                float4 xv = xp[(size_t)g * B_N];
                ACC_PAIR(plb + 2 * g,     g * 4,     xv.x, xv.y);
                ACC_PAIR(plb + 2 * g + 1, g * 4 + 2, xv.z, xv.w);
            }
        }
    }

    // horizontal add of packed halves
    float Pm[21], qv[6], quad;
    #pragma unroll
    for (int t = 0; t < 21; ++t) Pm[t] = Pm2[t].x + Pm2[t].y;
    #pragma unroll
    for (int t = 0; t < 6; ++t) qv[t] = qv2[t].x + qv2[t].y;
    quad = quad2.x + quad2.y;

    __syncthreads();                     // records dead; slab aliases them
    float* red = smem;                   // 64 x 33 slab, conflict-free
    #define SLAB_WR do { float* o = &red[s * 33]; \
        _Pragma("unroll") for (int t = 0; t < 21; ++t) o[t] = Pm[t]; \
        _Pragma("unroll") for (int t = 0; t < 6; ++t) o[21 + t] = qv[t]; \
        o[27] = quad; o[28] = (float)nob; } while (0)
    #define SLAB_ADD do { const float* o = &red[s * 33]; \
        _Pragma("unroll") for (int t = 0; t < 21; ++t) Pm[t] += o[t]; \
        _Pragma("unroll") for (int t = 0; t < 6; ++t) qv[t] += o[21 + t]; \
        quad += o[27]; nob += (int)o[28]; } while (0)

    if (h == 1) SLAB_WR;
    __syncthreads();
    if (h == 0) SLAB_ADD;
    __syncthreads();
    if (h == 3) SLAB_WR;
    __syncthreads();
    if (h == 2) SLAB_ADD;
    __syncthreads();
    if (h == 2) SLAB_WR;
    __syncthreads();
    if (h == 0) {
        SLAB_ADD;
        float nobs = (float)nob;

        // jld precomputed by k_jld into the scores buffer (read before overwrite)
        float jld = scores[(size_t)k * B_N + b];

        // P = I + sum
        Pm[0] += 1.f; Pm[2] += 1.f; Pm[5] += 1.f; Pm[9] += 1.f; Pm[14] += 1.f; Pm[20] += 1.f;

        float Lm[21], rd[6], sumlog;
        chol6(Pm, Lm, rd, &sumlog);
        float y[6];
        #pragma unroll
        for (int j = 0; j < 6; ++j) {
            float sv = qv[j];
            #pragma unroll
            for (int m = 0; m < j; ++m) sv -= Lm[IDX(j,m)] * y[m];
            y[j] = sv * rd[j];
        }
        float yy = 0.f;
        #pragma unroll
        for (int j = 0; j < 6; ++j) yy += y[j] * y[j];
        float logdet = 2.f * sumlog + jld;
        float ll = -0.5f * ((quad - yy) + logdet + nobs * LOG2PI_F);
        float score = ll + PI[k];

        scores[(size_t)k * B_N + b] = score;
        float* pq = Pq + (size_t)k * 27 * B_N + b;
        #pragma unroll
        for (int t = 0; t < 21; ++t) pq[(size_t)t * B_N] = Pm[t];
        #pragma unroll
        for (int t = 0; t < 6; ++t) pq[(size_t)(21 + t) * B_N] = qv[t];
    }
}

// ---------- KD: fused argmax + latent solve (wave 0 only) + output write ----------
// One block per sample. Argmax + 6x6 solve chain runs in wave 0 on
// block-uniform data (scalar loads), result broadcast through LDS; the full
// 256-thread block then streams M / A_out / D_out (write-bound, ~51 MB).
__global__ __launch_bounds__(256) void k_outsel(
        const float* __restrict__ scores, const float* __restrict__ Pq,
        const float* __restrict__ A, const float* __restrict__ MU,
        const float* __restrict__ logD, float* __restrict__ out) {
    __shared__ float smz[6];
    __shared__ float sLz[21];
    __shared__ int sc;
    const int b = blockIdx.x;
    const int tid = threadIdx.x;

    if (tid < 64) {
        // argmax over K (block-uniform -> scalar loads)
        float best = scores[b];
        int bc = 0;
        for (int kk = 1; kk < K_N; ++kk) {
            float sv = scores[(size_t)kk * B_N + b];
            if (sv > best) { best = sv; bc = kk; }
        }

        float Pm[21], qv[6];
        const float* pq = Pq + (size_t)bc * 27 * B_N + b;
        #pragma unroll
        for (int t = 0; t < 21; ++t) Pm[t] = pq[(size_t)t * B_N];
        #pragma unroll
        for (int t = 0; t < 6; ++t) qv[t] = pq[(size_t)(21 + t) * B_N];

        float Lm[21], rd[6], dummy;
        chol6(Pm, Lm, rd, &dummy);

        float y[6];
        #pragma unroll
        for (int j = 0; j < 6; ++j) {
            float sv = qv[j];
            #pragma unroll
            for (int m = 0; m < j; ++m) sv -= Lm[IDX(j,m)] * y[m];
            y[j] = sv * rd[j];
        }
        float mz[6];
        #pragma unroll
        for (int ii = 5; ii >= 0; --ii) {
            float sv = y[ii];
            #pragma unroll
            for (int j = ii + 1; j < 6; ++j) sv -= Lm[IDX(j,ii)] * mz[j];
            mz[ii] = sv * rd[ii];
        }
        float Li[21];
        #pragma unroll
        for (int j = 0; j < 6; ++j) {
            Li[IDX(j,j)] = rd[j];
            #pragma unroll
            for (int i = j + 1; i < 6; ++i) {
                float sv = 0.f;
                #pragma unroll
                for (int m = j; m < i; ++m) sv += Lm[IDX(i,m)] * Li[IDX(m,j)];
                Li[IDX(i,j)] = -sv * rd[i];
            }
        }
        float cov[21];
        #pragma unroll
        for (int i = 0; i < 6; ++i) {
            #pragma unroll
            for (int j = 0; j <= i; ++j) {
                float sv = 0.f;
                #pragma unroll
                for (int m = i; m < 6; ++m) sv += Li[IDX(m,i)] * Li[IDX(m,j)];
                cov[IDX(i,j)] = sv;
            }
        }
        float Lz[21], rd2[6];
        chol6(cov, Lz, rd2, &dummy);

        if (tid == 0) {
            sc = bc;
            out[OUT_PW + b] = 1.0f;
            #pragma unroll
            for (int t = 0; t < 6; ++t) smz[t] = mz[t];
            #pragma unroll
            for (int t = 0; t < 21; ++t) sLz[t] = Lz[t];
        }
    }
    __syncthreads();
    const int c = sc;

    for (int d = tid; d < D_FT; d += 256) {
        const float* ar = A + ((size_t)c * D_FT + d) * 6;
        float a[6];
        #pragma unroll
        for (int i = 0; i < 6; ++i) a[i] = ar[i];
        float mu = MU[(size_t)c * D_FT + d];
        float ld = logD[(size_t)c * D_FT + d];
        float m = mu;
        #pragma unroll
        for (int i = 0; i < 6; ++i) m += a[i] * smz[i];
        out[OUT_M + (size_t)b * D_FT + d] = m;
        out[OUT_D + (size_t)b * D_FT + d] = expf(ld);
        float* ao = out + OUT_A + ((size_t)b * D_FT + d) * 6;
        #pragma unroll
        for (int j = 0; j < 6; ++j) {
            float sv = 0.f;
            #pragma unroll
            for (int i = j; i < 6; ++i) sv += a[i] * sLz[IDX(i,j)];
            ao[j] = sv;
        }
    }
}

extern "C" void kernel_launch(void* const* d_in, const int* in_sizes, int n_in,
                              void* d_out, int out_size, void* d_ws, size_t ws_size,
                              hipStream_t stream) {
    (void)in_sizes; (void)n_in; (void)out_size; (void)ws_size;
    const float* X    = (const float*)d_in[0];
    const int*   J    = (const int*)d_in[1];
    const float* MU   = (const float*)d_in[2];
    const float* A    = (const float*)d_in[3];
    const float* logD = (const float*)d_in[4];
    const float* PI   = (const float*)d_in[5];
    float* out = (float*)d_out;
    float* ws  = (float*)d_ws;

    float*    scores = ws + WS_SCORES;   // pre-accum: SJL (jld terms)
    float*    Pq     = ws + WS_PQ;
    float4*   Xt4    = (float4*)(ws + WS_XT);
    unsigned* JbT    = (unsigned*)(ws + WS_JBT);

    k_prep<<<512, 1024, 0, stream>>>(X, J, Xt4, JbT);

    k_jld<<<K_N * 8, 256, 0, stream>>>(logD, JbT, scores);

    k_accum<<<32 * K_N, 256, 0, stream>>>(Xt4, JbT, A, MU, logD, PI, scores, Pq);

    k_outsel<<<B_N, 256, 0, stream>>>(scores, Pq, A, MU, logD, out);
}

// Round 11
// 114.402 us; speedup vs baseline: 1.2426x; 1.2127x over previous
//
#include <hip/hip_runtime.h>
#include <math.h>

#define B_N 2048
#define D_FT 784
#define K_N 50
#define L_N 6
#define LOG2PI_F 1.8378770664093453f

// ---- output layout (floats), concatenated in reference return order ----
#define OUT_PW 0
#define OUT_M  (B_N)                              // 2048
#define OUT_A  (OUT_M + B_N*D_FT)                 // 1607680
#define OUT_D  (OUT_A + B_N*D_FT*6)               // 11241472

// ---- workspace layout (float offsets) ----
#define WS_SCORES 0                                // [K][B]
#define WS_PQ     (WS_SCORES + K_N*B_N)            // [K][27][B] 2764800
#define WS_XT     (WS_PQ + K_N*27*B_N)             // [D/4][B] float4 = D*B floats
#define WS_JBT    (WS_XT + D_FT*B_N)               // [25][B]    51200

#define IDX(i,j) ((i)*((i)+1)/2 + (j))   // packed lower, i>=j

typedef float v2f __attribute__((ext_vector_type(2)));

// VOP3P packed f32 (halves VALU issue slots for the accumulator updates).
#define PK_FMA(acc, a, b) asm("v_pk_fma_f32 %0, %1, %2, %0" : "+v"(acc) : "v"(a), "v"(b))

// ---------- 6x6 packed-lower Cholesky ----------
__device__ __forceinline__ void chol6(const float* P, float* L, float* rd, float* sumlog) {
    float sl = 0.f;
    #pragma unroll
    for (int j = 0; j < 6; ++j) {
        float s = P[IDX(j,j)];
        #pragma unroll
        for (int m = 0; m < j; ++m) s -= L[IDX(j,m)] * L[IDX(j,m)];
        float d = sqrtf(s);
        L[IDX(j,j)] = d;
        float r = 1.0f / d;
        rd[j] = r;
        sl += logf(d);
        #pragma unroll
        for (int i = j + 1; i < 6; ++i) {
            float t = P[IDX(i,j)];
            #pragma unroll
            for (int m = 0; m < j; ++m) t -= L[IDX(i,m)] * L[IDX(j,m)];
            L[IDX(i,j)] = t * r;
        }
    }
    *sumlog = sl;
}

// ---------- K0: fused transpose (X -> Xt4) + packbits (J -> JbT) ----------
__global__ __launch_bounds__(1024) void k_prep(const float* __restrict__ X,
                                               const int* __restrict__ J,
                                               float4* __restrict__ Xt4,
                                               unsigned* __restrict__ JbT) {
    const int bid = blockIdx.x;
    const int tid = threadIdx.x;
    if (bid < 448) {
        __shared__ float4 tile[32][33];
        int tx = tid & 31, ty = tid >> 5;
        int d4b = (bid % 7) * 32;
        int bb  = (bid / 7) * 32;
        int d4 = d4b + tx;
        if (d4 < D_FT / 4)
            tile[ty][tx] = *(const float4*)&X[(size_t)(bb + ty) * D_FT + d4 * 4];
        __syncthreads();
        int d4o = d4b + ty;
        if (d4o < D_FT / 4)
            Xt4[(size_t)d4o * B_N + (bb + tx)] = tile[tx][ty];
    } else {
        int t = (bid - 448) * 1024 + tid;    // 65536 threads = 2048 b x 32 w
        int b = t >> 5;
        int w = t & 31;
        if (w >= 25) return;
        int d0 = w * 32;
        int n = D_FT - d0; if (n > 32) n = 32;
        unsigned u = 0;
        for (int j = 0; j < n; ++j)
            u |= (J[(size_t)b * D_FT + d0 + j] != 0 ? 1u : 0u) << j;
        JbT[(size_t)w * B_N + b] = u;
    }
}

// ---------- K1: per-(sample,k) accumulation + loglik ----------
// 256 threads = 64 samples x 4 d-quarters; d staged in two chunks through a
// 12.8 KB LDS record buffer + 1.6 KB logD-pair array (jld folded in; the
// separate k_jld kernel is gone). Per mask-word the 8 x-float4 loads are
// HOISTED into a register array so all 8 VMEM ops are in flight before the 16
// ACC_PAIRs consume them (covers ~1200 cyc >> L2 latency).
// launch_bounds(256,3): the min-waves=4 bound made the allocator PIN at the
// 64-VGPR occupancy step and spill the hoist (r9: 26.9MB scratch). min-waves=3
// raises the cap so the hoist can live in registers (~96 VGPR, ~21 waves/CU).
// min-waves>=6 is catastrophic (r3/r4). Records must be LDS-resident (r7).
// Math (m^2=m): u_i = m*a~_i; P_ij += u_i*u_j; z = (m*sa)*(x-mu);
//               q_j += z*u_j; quad += z*z; jld += m*logD.
#define ACC_PAIR(pi, dd, x0, x1) do { \
    const float4 f0 = sm4[(size_t)(pi) * 4 + 0]; \
    const float4 f1 = sm4[(size_t)(pi) * 4 + 1]; \
    const float4 f2 = sm4[(size_t)(pi) * 4 + 2]; \
    const float4 f3 = sm4[(size_t)(pi) * 4 + 3]; \
    const v2f l2 = sldp[(pi)]; \
    v2f m2;  m2.x = (float)((mw >> (dd)) & 1u); m2.y = (float)((mw >> ((dd)+1)) & 1u); \
    v2f x2;  x2.x = (x0); x2.y = (x1); \
    v2f sa2;  sa2.x = f3.x;  sa2.y = f3.y; \
    v2f nmu2; nmu2.x = f3.z; nmu2.y = f3.w; \
    v2f xm2 = x2 + nmu2; \
    v2f w2  = m2 * sa2; \
    v2f z2  = w2 * xm2; \
    v2f a0; a0.x = f0.x; a0.y = f0.y;  v2f a1; a1.x = f0.z; a1.y = f0.w; \
    v2f a2; a2.x = f1.x; a2.y = f1.y;  v2f a3; a3.x = f1.z; a3.y = f1.w; \
    v2f a4; a4.x = f2.x; a4.y = f2.y;  v2f a5; a5.x = f2.z; a5.y = f2.w; \
    v2f u0 = m2 * a0, u1 = m2 * a1, u2 = m2 * a2; \
    v2f u3 = m2 * a3, u4 = m2 * a4, u5 = m2 * a5; \
    PK_FMA(jld2, m2, l2); \
    PK_FMA(Pm2[0],  u0, u0); \
    PK_FMA(Pm2[1],  u1, u0); PK_FMA(Pm2[2],  u1, u1); \
    PK_FMA(Pm2[3],  u2, u0); PK_FMA(Pm2[4],  u2, u1); PK_FMA(Pm2[5],  u2, u2); \
    PK_FMA(Pm2[6],  u3, u0); PK_FMA(Pm2[7],  u3, u1); PK_FMA(Pm2[8],  u3, u2); PK_FMA(Pm2[9],  u3, u3); \
    PK_FMA(Pm2[10], u4, u0); PK_FMA(Pm2[11], u4, u1); PK_FMA(Pm2[12], u4, u2); PK_FMA(Pm2[13], u4, u3); PK_FMA(Pm2[14], u4, u4); \
    PK_FMA(Pm2[15], u5, u0); PK_FMA(Pm2[16], u5, u1); PK_FMA(Pm2[17], u5, u2); PK_FMA(Pm2[18], u5, u3); PK_FMA(Pm2[19], u5, u4); PK_FMA(Pm2[20], u5, u5); \
    PK_FMA(qv2[0], z2, u0); PK_FMA(qv2[1], z2, u1); PK_FMA(qv2[2], z2, u2); \
    PK_FMA(qv2[3], z2, u3); PK_FMA(qv2[4], z2, u4); PK_FMA(qv2[5], z2, u5); \
    PK_FMA(quad2, z2, z2); \
} while (0)

__global__ __launch_bounds__(256, 3) void k_accum(
        const float4* __restrict__ Xt4, const unsigned* __restrict__ JbT,
        const float* __restrict__ A, const float* __restrict__ MU,
        const float* __restrict__ logD, const float* __restrict__ PI,
        float* __restrict__ scores, float* __restrict__ Pq) {
    __shared__ float4 sm4[200 * 4];     // 12800 B records; aliased as merge slab
    __shared__ v2f sldp[200];           // 1600 B logD pairs
    float* smem = (float*)sm4;
    const int k   = blockIdx.x >> 5;
    const int tid = threadIdx.x;
    const int s   = tid & 63;
    const int h   = tid >> 6;           // d-quarter 0..3
    const int b   = (blockIdx.x & 31) * 64 + s;

    v2f Pm2[21], qv2[6], quad2, jld2;
    #pragma unroll
    for (int t = 0; t < 21; ++t) { Pm2[t].x = 0.f; Pm2[t].y = 0.f; }
    #pragma unroll
    for (int t = 0; t < 6; ++t) { qv2[t].x = 0.f; qv2[t].y = 0.f; }
    quad2.x = 0.f; quad2.y = 0.f;
    jld2.x = 0.f; jld2.y = 0.f;
    int nob = 0;

    for (int c = 0; c < 2; ++c) {
        const int dbase = c ? 384 : 0;
        const int npair = c ? 200 : 192;
        __syncthreads();                 // all quarters done reading old records
        for (int p = tid; p < npair; p += 256) {
            const int d0 = dbase + 2 * p;
            const float* ar0 = A + ((size_t)k * D_FT + d0) * 6;
            const float* ar1 = ar0 + 6;
            float ld0 = logD[(size_t)k * D_FT + d0];
            float ld1 = logD[(size_t)k * D_FT + d0 + 1];
            float sa0 = expf(-0.5f * ld0);
            float sa1 = expf(-0.5f * ld1);
            float4 f0, f1, f2, f3;
            f0.x = sa0 * ar0[0]; f0.y = sa1 * ar1[0]; f0.z = sa0 * ar0[1]; f0.w = sa1 * ar1[1];
            f1.x = sa0 * ar0[2]; f1.y = sa1 * ar1[2]; f1.z = sa0 * ar0[3]; f1.w = sa1 * ar1[3];
            f2.x = sa0 * ar0[4]; f2.y = sa1 * ar1[4]; f2.z = sa0 * ar0[5]; f2.w = sa1 * ar1[5];
            f3.x = sa0; f3.y = sa1;
            f3.z = -MU[(size_t)k * D_FT + d0];
            f3.w = -MU[(size_t)k * D_FT + d0 + 1];
            sm4[(size_t)p * 4 + 0] = f0;
            sm4[(size_t)p * 4 + 1] = f1;
            sm4[(size_t)p * 4 + 2] = f2;
            sm4[(size_t)p * 4 + 3] = f3;
            v2f lp; lp.x = ld0; lp.y = ld1;
            sldp[p] = lp;
        }
        __syncthreads();

        const int wb = (c ? 12 : 0) + 3 * h;
        for (int w = wb; w < wb + 3; ++w) {
            const unsigned mw = JbT[(size_t)w * B_N + b];
            nob += __popc(mw);
            const int plb = w * 16 - (dbase >> 1);   // local pair base
            const float4* xp = Xt4 + (size_t)(w * 8) * B_N + b;
            float4 xv[8];
            #pragma unroll
            for (int g = 0; g < 8; ++g) xv[g] = xp[(size_t)g * B_N];
            #pragma unroll
            for (int g = 0; g < 8; ++g) {
                ACC_PAIR(plb + 2 * g,     g * 4,     xv[g].x, xv[g].y);
                ACC_PAIR(plb + 2 * g + 1, g * 4 + 2, xv[g].z, xv[g].w);
            }
        }
        if (c == 1 && h == 3) {  // tail word 24: bits 0..15 valid
            const unsigned mw = JbT[(size_t)24 * B_N + b];
            nob += __popc(mw);
            const int plb = 24 * 16 - 192;           // = 192
            const float4* xp = Xt4 + (size_t)(24 * 8) * B_N + b;
            float4 xv[4];
            #pragma unroll
            for (int g = 0; g < 4; ++g) xv[g] = xp[(size_t)g * B_N];
            #pragma unroll
            for (int g = 0; g < 4; ++g) {
                ACC_PAIR(plb + 2 * g,     g * 4,     xv[g].x, xv[g].y);
                ACC_PAIR(plb + 2 * g + 1, g * 4 + 2, xv[g].z, xv[g].w);
            }
        }
    }

    // horizontal add of packed halves
    float Pm[21], qv[6], quad, jld;
    #pragma unroll
    for (int t = 0; t < 21; ++t) Pm[t] = Pm2[t].x + Pm2[t].y;
    #pragma unroll
    for (int t = 0; t < 6; ++t) qv[t] = qv2[t].x + qv2[t].y;
    quad = quad2.x + quad2.y;
    jld  = jld2.x + jld2.y;

    __syncthreads();                     // records dead; slab aliases them
    float* red = smem;                   // 64 x 33 slab, conflict-free
    #define SLAB_WR do { float* o = &red[s * 33]; \
        _Pragma("unroll") for (int t = 0; t < 21; ++t) o[t] = Pm[t]; \
        _Pragma("unroll") for (int t = 0; t < 6; ++t) o[21 + t] = qv[t]; \
        o[27] = quad; o[28] = (float)nob; o[29] = jld; } while (0)
    #define SLAB_ADD do { const float* o = &red[s * 33]; \
        _Pragma("unroll") for (int t = 0; t < 21; ++t) Pm[t] += o[t]; \
        _Pragma("unroll") for (int t = 0; t < 6; ++t) qv[t] += o[21 + t]; \
        quad += o[27]; nob += (int)o[28]; jld += o[29]; } while (0)

    if (h == 1) SLAB_WR;
    __syncthreads();
    if (h == 0) SLAB_ADD;
    __syncthreads();
    if (h == 3) SLAB_WR;
    __syncthreads();
    if (h == 2) SLAB_ADD;
    __syncthreads();
    if (h == 2) SLAB_WR;
    __syncthreads();
    if (h == 0) {
        SLAB_ADD;
        float nobs = (float)nob;

        // P = I + sum
        Pm[0] += 1.f; Pm[2] += 1.f; Pm[5] += 1.f; Pm[9] += 1.f; Pm[14] += 1.f; Pm[20] += 1.f;

        float Lm[21], rd[6], sumlog;
        chol6(Pm, Lm, rd, &sumlog);
        float y[6];
        #pragma unroll
        for (int j = 0; j < 6; ++j) {
            float sv = qv[j];
            #pragma unroll
            for (int m = 0; m < j; ++m) sv -= Lm[IDX(j,m)] * y[m];
            y[j] = sv * rd[j];
        }
        float yy = 0.f;
        #pragma unroll
        for (int j = 0; j < 6; ++j) yy += y[j] * y[j];
        float logdet = 2.f * sumlog + jld;
        float ll = -0.5f * ((quad - yy) + logdet + nobs * LOG2PI_F);
        float score = ll + PI[k];

        scores[(size_t)k * B_N + b] = score;
        float* pq = Pq + (size_t)k * 27 * B_N + b;
        #pragma unroll
        for (int t = 0; t < 21; ++t) pq[(size_t)t * B_N] = Pm[t];
        #pragma unroll
        for (int t = 0; t < 6; ++t) pq[(size_t)(21 + t) * B_N] = qv[t];
    }
}

// ---------- KD: fused argmax + latent solve (wave 0 only) + output write ----------
__global__ __launch_bounds__(256) void k_outsel(
        const float* __restrict__ scores, const float* __restrict__ Pq,
        const float* __restrict__ A, const float* __restrict__ MU,
        const float* __restrict__ logD, float* __restrict__ out) {
    __shared__ float smz[6];
    __shared__ float sLz[21];
    __shared__ int sc;
    const int b = blockIdx.x;
    const int tid = threadIdx.x;

    if (tid < 64) {
        float best = scores[b];
        int bc = 0;
        for (int kk = 1; kk < K_N; ++kk) {
            float sv = scores[(size_t)kk * B_N + b];
            if (sv > best) { best = sv; bc = kk; }
        }

        float Pm[21], qv[6];
        const float* pq = Pq + (size_t)bc * 27 * B_N + b;
        #pragma unroll
        for (int t = 0; t < 21; ++t) Pm[t] = pq[(size_t)t * B_N];
        #pragma unroll
        for (int t = 0; t < 6; ++t) qv[t] = pq[(size_t)(21 + t) * B_N];

        float Lm[21], rd[6], dummy;
        chol6(Pm, Lm, rd, &dummy);

        float y[6];
        #pragma unroll
        for (int j = 0; j < 6; ++j) {
            float sv = qv[j];
            #pragma unroll
            for (int m = 0; m < j; ++m) sv -= Lm[IDX(j,m)] * y[m];
            y[j] = sv * rd[j];
        }
        float mz[6];
        #pragma unroll
        for (int ii = 5; ii >= 0; --ii) {
            float sv = y[ii];
            #pragma unroll
            for (int j = ii + 1; j < 6; ++j) sv -= Lm[IDX(j,ii)] * mz[j];
            mz[ii] = sv * rd[ii];
        }
        float Li[21];
        #pragma unroll
        for (int j = 0; j < 6; ++j) {
            Li[IDX(j,j)] = rd[j];
            #pragma unroll
            for (int i = j + 1; i < 6; ++i) {
                float sv = 0.f;
                #pragma unroll
                for (int m = j; m < i; ++m) sv += Lm[IDX(i,m)] * Li[IDX(m,j)];
                Li[IDX(i,j)] = -sv * rd[i];
            }
        }
        float cov[21];
        #pragma unroll
        for (int i = 0; i < 6; ++i) {
            #pragma unroll
            for (int j = 0; j <= i; ++j) {
                float sv = 0.f;
                #pragma unroll
                for (int m = i; m < 6; ++m) sv += Li[IDX(m,i)] * Li[IDX(m,j)];
                cov[IDX(i,j)] = sv;
            }
        }
        float Lz[21], rd2[6];
        chol6(cov, Lz, rd2, &dummy);

        if (tid == 0) {
            sc = bc;
            out[OUT_PW + b] = 1.0f;
            #pragma unroll
            for (int t = 0; t < 6; ++t) smz[t] = mz[t];
            #pragma unroll
            for (int t = 0; t < 21; ++t) sLz[t] = Lz[t];
        }
    }
    __syncthreads();
    const int c = sc;

    for (int d = tid; d < D_FT; d += 256) {
        const float* ar = A + ((size_t)c * D_FT + d) * 6;
        float a[6];
        #pragma unroll
        for (int i = 0; i < 6; ++i) a[i] = ar[i];
        float mu = MU[(size_t)c * D_FT + d];
        float ld = logD[(size_t)c * D_FT + d];
        float m = mu;
        #pragma unroll
        for (int i = 0; i < 6; ++i) m += a[i] * smz[i];
        out[OUT_M + (size_t)b * D_FT + d] = m;
        out[OUT_D + (size_t)b * D_FT + d] = expf(ld);
        float* ao = out + OUT_A + ((size_t)b * D_FT + d) * 6;
        #pragma unroll
        for (int j = 0; j < 6; ++j) {
            float sv = 0.f;
            #pragma unroll
            for (int i = j; i < 6; ++i) sv += a[i] * sLz[IDX(i,j)];
            ao[j] = sv;
        }
    }
}

extern "C" void kernel_launch(void* const* d_in, const int* in_sizes, int n_in,
                              void* d_out, int out_size, void* d_ws, size_t ws_size,
                              hipStream_t stream) {
    (void)in_sizes; (void)n_in; (void)out_size; (void)ws_size;
    const float* X    = (const float*)d_in[0];
    const int*   J    = (const int*)d_in[1];
    const float* MU   = (const float*)d_in[2];
    const float* A    = (const float*)d_in[3];
    const float* logD = (const float*)d_in[4];
    const float* PI   = (const float*)d_in[5];
    float* out = (float*)d_out;
    float* ws  = (float*)d_ws;

    float*    scores = ws + WS_SCORES;
    float*    Pq     = ws + WS_PQ;
    float4*   Xt4    = (float4*)(ws + WS_XT);
    unsigned* JbT    = (unsigned*)(ws + WS_JBT);

    k_prep<<<512, 1024, 0, stream>>>(X, J, Xt4, JbT);

    k_accum<<<32 * K_N, 256, 0, stream>>>(Xt4, JbT, A, MU, logD, PI, scores, Pq);

    k_outsel<<<B_N, 256, 0, stream>>>(scores, Pq, A, MU, logD, out);
}